// Round 14
// baseline (3523.388 us; speedup 1.0000x reference)
//
#include <hip/hip_runtime.h>
#include <hip/hip_bf16.h>
#include <string.h>

// LSTMFeatureExtractor: 2-layer LSTM (H=64, IN=1, B=2048, T=512) + FC(64->32)+ReLU
// R17b = R17 with compile fixes (cvt_pkrtz type mismatch -> plain _Float16
// casts; (void) on hipMemsetAsync). Layer-split producer/consumer BLOCKS:
// L0-block (4 waves x 8 MFMA) + L1-block (4 waves x 16 MFMA) = same 24
// MFMA/SIMD/step as R15, per-block HW barriers, L0->L1 handoff via a 4-slot
// h0 ring in workspace with agent-scope atomics + slack (prefetch 1 ahead,
// cached flags -> polls usually free). Flags zeroed per launch by captured
// hipMemsetAsync. Falls back to the R15 kernel if ws_size too small.

#define HID 64
#define TSTEPS 512
#define MB 8
#define RS 80
#define WS_NEED (4096 + 256 * 4096)   // flags (4KB) + 256 pairs x 4KB ring

typedef _Float16 f16x8 __attribute__((ext_vector_type(8)));
typedef _Float16 f16x2 __attribute__((ext_vector_type(2)));
typedef float f32x4 __attribute__((ext_vector_type(4)));
typedef float f32x2 __attribute__((ext_vector_type(2)));

#define KSIG (-1.44269504089f)
#define KTANH (2.88539008178f)

__device__ __forceinline__ f32x2 mk2(float a, float b) { f32x2 r; r[0] = a; r[1] = b; return r; }
__device__ __forceinline__ f32x2 exp2v(f32x2 v) {
    f32x2 r; r[0] = __builtin_amdgcn_exp2f(v[0]); r[1] = __builtin_amdgcn_exp2f(v[1]); return r;
}
__device__ __forceinline__ f32x2 rcpv(f32x2 v) {
    f32x2 r; r[0] = __builtin_amdgcn_rcpf(v[0]); r[1] = __builtin_amdgcn_rcpf(v[1]); return r;
}

#define MFMA16(A, B, C) __builtin_amdgcn_mfma_f32_16x16x32_f16((A), (B), (C), 0, 0, 0)

union U16x8 { unsigned u[4]; f16x8 v; };
union UPK   { f16x2 h; unsigned u; };

// ---- fused cell (7 trans), updates cc ----
#define FCELL(PI, PF, PG, PO, HH) do {                                               \
    f32x2 ea = exp2v(PI), eb = exp2v(PF), eg = exp2v(PG), ed = exp2v(PO);            \
    f32x2 Aq = ea + 1.f, Bq = eb + 1.f, Gp = eg + 1.f, Dn = ed + 1.f;                \
    f32x2 AG = Aq * Gp;                                                              \
    f32x2 r1 = rcpv(AG * Bq);                                                        \
    f32x2 nm = cc * AG + (eg - 1.f) * Bq;                                            \
    cc = nm * r1;                                                                    \
    f32x2 E  = exp2v(cc * KTANH);                                                    \
    f32x2 r2 = rcpv(Dn * (E + 1.f));                                                 \
    HH = (E - 1.f) * r2;                                                             \
} while (0)

// ======================= producer/consumer kernel =======================
__global__ __launch_bounds__(256, 2) void lstm_pc_kernel(
    const float* __restrict__ x,
    const float* __restrict__ Wih0, const float* __restrict__ Whh0,
    const float* __restrict__ bih0, const float* __restrict__ bhh0,
    const float* __restrict__ Wih1, const float* __restrict__ Whh1,
    const float* __restrict__ bih1, const float* __restrict__ bhh1,
    const float* __restrict__ fcW, const float* __restrict__ fcb,
    float* __restrict__ out, unsigned* __restrict__ ws)
{
    // producer LDS
    __shared__ __align__(16) float x_lds[4 * TSTEPS * 2];        // 16 KB
    __shared__ __align__(16) _Float16 h0_lds[2][MB * RS];
    // consumer LDS
    __shared__ __align__(16) _Float16 h1_lds[2][MB * RS];
    __shared__ float h1f32[MB * HID];
    __shared__ float fcw_lds[HID * 32];
    __shared__ float fcb_lds[32];

    const int b    = blockIdx.x;
    const int slot = b >> 3;
    const int role = slot & 1;                 // 0 = L0 producer, 1 = L1 consumer
    const int pair = (b & 7) * 32 + (slot >> 1);
    const int bbase = pair * MB;

    const int tid  = threadIdx.x;
    const int wave = tid >> 6;                 // 0..3
    const int lane = tid & 63;
    const int nq   = lane & 15;
    const int quad = lane >> 4;
    const int u    = wave * 16 + nq;

    unsigned* prodp = ws + pair;
    unsigned* consp = ws + 256 + pair;
    unsigned* ring  = ws + 1024 + pair * 1024; // 4 slots x 256 u32

    const int arow = (nq >> 1) * RS + quad * 8;
    const int b0r  = (quad * 2) * RS;
    const int hbase = quad * 2;
    f32x2 cc = mk2(0.f, 0.f);
    const f32x4 zero4 = {0.f, 0.f, 0.f, 0.f};

#define POLLP(N) do { if (lastp < (N)) { for (;;) {                                  \
    unsigned v_ = 0;                                                                 \
    if (lane == 0) v_ = __hip_atomic_load(prodp, __ATOMIC_RELAXED, __HIP_MEMORY_SCOPE_AGENT); \
    lastp = __shfl((int)v_, 0);                                                      \
    if (lastp >= (N)) break;                                                         \
    __builtin_amdgcn_s_sleep(2); } } } while (0)

#define POLLC(N) do { if (lastc < (N)) { for (;;) {                                  \
    unsigned v_ = 0;                                                                 \
    if (lane == 0) v_ = __hip_atomic_load(consp, __ATOMIC_RELAXED, __HIP_MEMORY_SCOPE_AGENT); \
    lastc = __shfl((int)v_, 0);                                                      \
    if (lastc >= (N)) break;                                                         \
    __builtin_amdgcn_s_sleep(2); } } } while (0)

    if (role == 0) {
        // =========================== PRODUCER (L0) ===========================
        for (int i = tid; i < TSTEPS * MB; i += 256) {
            int r = i >> 9, t = i & (TSTEPS - 1);
            x_lds[(r >> 1) * (TSTEPS * 2) + t * 2 + (r & 1)] = x[(bbase + r) * TSTEPS + t];
        }
        for (int i = tid; i < 2 * MB * RS; i += 256) ((_Float16*)h0_lds)[i] = (_Float16)0.f;

        f16x8 w0[4][2];
        f32x4 cbias[4];
        float wx0s[4];
        #pragma unroll
        for (int g = 0; g < 4; ++g) {
            const float sc = (g == 2) ? KTANH : KSIG;
            const int n = g * 64 + u;
            const float bs = (bih0[n] + bhh0[n]) * sc;
            cbias[g] = (f32x4){bs, bs, bs, bs};
            wx0s[g] = Wih0[n] * sc;
            #pragma unroll
            for (int ks = 0; ks < 2; ++ks) {
                const int k0 = quad * 8 + ks * 32;
                f16x8 a;
                #pragma unroll
                for (int j = 0; j < 8; ++j) a[j] = (_Float16)(Whh0[n * HID + k0 + j] * sc);
                w0[g][ks] = a;
            }
        }
        const int wwi = (2 * quad + (lane & 1)) * 32 + wave * 8 + (nq >> 1);
        int lastc = 0;
        __syncthreads();

#define P_STEP(P, Q, J, XQ2) do {                                                    \
    f16x8 a0_ = *(const f16x8*)&h0_lds[P][arow];                                     \
    f16x8 a1_ = *(const f16x8*)&h0_lds[P][arow + 32];                                \
    f32x4 ac[4];                                                                     \
    __builtin_amdgcn_s_setprio(1);                                                   \
    _Pragma("unroll")                                                                \
    for (int g = 0; g < 4; ++g) ac[g] = MFMA16(a0_, w0[g][0], cbias[g]);             \
    _Pragma("unroll")                                                                \
    for (int g = 0; g < 4; ++g) ac[g] = MFMA16(a1_, w0[g][1], ac[g]);                \
    __builtin_amdgcn_s_setprio(0);                                                   \
    f32x2 pi = (XQ2) * wx0s[0] + mk2(ac[0][0], ac[0][2]);                            \
    f32x2 pf = (XQ2) * wx0s[1] + mk2(ac[1][0], ac[1][2]);                            \
    f32x2 pg = (XQ2) * wx0s[2] + mk2(ac[2][0], ac[2][2]);                            \
    f32x2 po = (XQ2) * wx0s[3] + mk2(ac[3][0], ac[3][2]);                            \
    f32x2 hh;                                                                        \
    FCELL(pi, pf, pg, po, hh);                                                       \
    h0_lds[Q][b0r + u]      = (_Float16)hh[0];                                       \
    h0_lds[Q][b0r + RS + u] = (_Float16)hh[1];                                       \
    POLLC((J) - 3);                                                                  \
    float pd = __shfl_down(hh[0], 1);                                                \
    float pu = __shfl_up(hh[1], 1);                                                  \
    UPK pk_;                                                                         \
    if (lane & 1) { pk_.h[0] = (_Float16)pu;    pk_.h[1] = (_Float16)hh[1]; }        \
    else          { pk_.h[0] = (_Float16)hh[0]; pk_.h[1] = (_Float16)pd;    }        \
    __hip_atomic_store(ring + ((((J) + 1) & 3) << 8) + wwi, pk_.u,                   \
                       __ATOMIC_RELAXED, __HIP_MEMORY_SCOPE_AGENT);                  \
    asm volatile("s_waitcnt vmcnt(1)" ::: "memory");                                 \
} while (0)

        const int xoff = quad * (TSTEPS * 2);
        for (int j = 0; j < TSTEPS; j += 2) {
            if (tid == 0 && j)
                __hip_atomic_store(prodp, (unsigned)(j - 1), __ATOMIC_RELAXED, __HIP_MEMORY_SCOPE_AGENT);
            const f32x4 xv = *(const f32x4*)&x_lds[xoff + j * 2];
            P_STEP(0, 1, j, mk2(xv[0], xv[1]));
            __syncthreads();
            if (tid == 0)
                __hip_atomic_store(prodp, (unsigned)j, __ATOMIC_RELAXED, __HIP_MEMORY_SCOPE_AGENT);
            P_STEP(1, 0, j + 1, mk2(xv[2], xv[3]));
            __syncthreads();
        }
        asm volatile("s_waitcnt vmcnt(0)" ::: "memory");
        __syncthreads();
        if (tid == 0)
            __hip_atomic_store(prodp, (unsigned)TSTEPS, __ATOMIC_RELAXED, __HIP_MEMORY_SCOPE_AGENT);
    } else {
        // =========================== CONSUMER (L1) ===========================
        for (int i = tid; i < 32 * HID; i += 256) {
            int o = i >> 6, kk = i & 63;
            fcw_lds[kk * 32 + o] = fcW[i];
        }
        if (tid < 32) fcb_lds[tid] = fcb[tid];
        for (int i = tid; i < 2 * MB * RS; i += 256) ((_Float16*)h1_lds)[i] = (_Float16)0.f;

        f16x8 wi1[4][2], wh1[4][2];
        f32x4 cbias[4];
        #pragma unroll
        for (int g = 0; g < 4; ++g) {
            const float sc = (g == 2) ? KTANH : KSIG;
            const int n = g * 64 + u;
            const float bs = (bih1[n] + bhh1[n]) * sc;
            cbias[g] = (f32x4){bs, bs, bs, bs};
            #pragma unroll
            for (int ks = 0; ks < 2; ++ks) {
                const int k0 = quad * 8 + ks * 32;
                f16x8 a1, b1;
                #pragma unroll
                for (int j = 0; j < 8; ++j) {
                    a1[j] = (_Float16)(Wih1[n * HID + k0 + j] * sc);
                    b1[j] = (_Float16)(Whh1[n * HID + k0 + j] * sc);
                }
                wi1[g][ks] = a1; wh1[g][ks] = b1;
            }
        }
        const unsigned wbase = (unsigned)((nq >> 1) * 32 + quad * 4);
        unsigned gA[8], gB[8];
        int lastp = 0;
        __syncthreads();

#define PREFETCH(K, G) do {                                                          \
    const unsigned* rp_ = ring + (((K) & 3) << 8) + wbase;                           \
    _Pragma("unroll")                                                                \
    for (int i = 0; i < 4; ++i)                                                      \
        G[i] = __hip_atomic_load(rp_ + i, __ATOMIC_RELAXED, __HIP_MEMORY_SCOPE_AGENT); \
    _Pragma("unroll")                                                                \
    for (int i = 0; i < 4; ++i)                                                      \
        G[4 + i] = __hip_atomic_load(rp_ + 16 + i, __ATOMIC_RELAXED, __HIP_MEMORY_SCOPE_AGENT); \
} while (0)

#define C_STEP(RB, WB, G) do {                                                       \
    U16x8 t0_, t1_;                                                                  \
    t0_.u[0] = G[0]; t0_.u[1] = G[1]; t0_.u[2] = G[2]; t0_.u[3] = G[3];              \
    t1_.u[0] = G[4]; t1_.u[1] = G[5]; t1_.u[2] = G[6]; t1_.u[3] = G[7];              \
    f16x8 b0v = *(const f16x8*)&h1_lds[RB][arow];                                    \
    f16x8 b1v = *(const f16x8*)&h1_lds[RB][arow + 32];                               \
    f32x4 aA[4], aB[4];                                                              \
    __builtin_amdgcn_s_setprio(1);                                                   \
    _Pragma("unroll")                                                                \
    for (int g = 0; g < 4; ++g) aA[g] = MFMA16(t0_.v, wi1[g][0], cbias[g]);          \
    _Pragma("unroll")                                                                \
    for (int g = 0; g < 4; ++g) aA[g] = MFMA16(t1_.v, wi1[g][1], aA[g]);             \
    _Pragma("unroll")                                                                \
    for (int g = 0; g < 4; ++g) aB[g] = MFMA16(b0v, wh1[g][0], zero4);               \
    _Pragma("unroll")                                                                \
    for (int g = 0; g < 4; ++g) aB[g] = MFMA16(b1v, wh1[g][1], aB[g]);               \
    __builtin_amdgcn_s_setprio(0);                                                   \
    f32x2 pi = mk2(aA[0][0], aA[0][2]) + mk2(aB[0][0], aB[0][2]);                    \
    f32x2 pf = mk2(aA[1][0], aA[1][2]) + mk2(aB[1][0], aB[1][2]);                    \
    f32x2 pg = mk2(aA[2][0], aA[2][2]) + mk2(aB[2][0], aB[2][2]);                    \
    f32x2 po = mk2(aA[3][0], aA[3][2]) + mk2(aB[3][0], aB[3][2]);                    \
    f32x2 hh;                                                                        \
    FCELL(pi, pf, pg, po, hh);                                                       \
    h1_lds[WB][b0r + u]      = (_Float16)hh[0];                                      \
    h1_lds[WB][b0r + RS + u] = (_Float16)hh[1];                                      \
} while (0)

        POLLP(1);
        PREFETCH(1, gA);
        for (int k = 1; k <= TSTEPS - 3; k += 2) {      // steps k (gA), k+1 (gB)
            if (tid == 0)
                __hip_atomic_store(consp, (unsigned)(k - 1), __ATOMIC_RELAXED, __HIP_MEMORY_SCOPE_AGENT);
            C_STEP(0, 1, gA);
            POLLP(k + 1);
            PREFETCH(k + 1, gB);
            __syncthreads();
            if (tid == 0)
                __hip_atomic_store(consp, (unsigned)k, __ATOMIC_RELAXED, __HIP_MEMORY_SCOPE_AGENT);
            C_STEP(1, 0, gB);
            POLLP(k + 2);
            PREFETCH(k + 2, gA);
            __syncthreads();
        }
        // k = 511 (gA): read h1 buf0, write buf1
        if (tid == 0)
            __hip_atomic_store(consp, 510u, __ATOMIC_RELAXED, __HIP_MEMORY_SCOPE_AGENT);
        C_STEP(0, 1, gA);
        POLLP(TSTEPS);
        PREFETCH(TSTEPS, gB);
        __syncthreads();
        // k = 512 final (gB): read h1 buf1 -> h1f32
        if (tid == 0)
            __hip_atomic_store(consp, 511u, __ATOMIC_RELAXED, __HIP_MEMORY_SCOPE_AGENT);
        {
            U16x8 t0_, t1_;
            t0_.u[0] = gB[0]; t0_.u[1] = gB[1]; t0_.u[2] = gB[2]; t0_.u[3] = gB[3];
            t1_.u[0] = gB[4]; t1_.u[1] = gB[5]; t1_.u[2] = gB[6]; t1_.u[3] = gB[7];
            f16x8 b0v = *(const f16x8*)&h1_lds[1][arow];
            f16x8 b1v = *(const f16x8*)&h1_lds[1][arow + 32];
            f32x4 aA[4], aB[4];
            #pragma unroll
            for (int g = 0; g < 4; ++g) aA[g] = MFMA16(t0_.v, wi1[g][0], cbias[g]);
            #pragma unroll
            for (int g = 0; g < 4; ++g) aA[g] = MFMA16(t1_.v, wi1[g][1], aA[g]);
            #pragma unroll
            for (int g = 0; g < 4; ++g) aB[g] = MFMA16(b0v, wh1[g][0], zero4);
            #pragma unroll
            for (int g = 0; g < 4; ++g) aB[g] = MFMA16(b1v, wh1[g][1], aB[g]);
            f32x2 pi = mk2(aA[0][0], aA[0][2]) + mk2(aB[0][0], aB[0][2]);
            f32x2 pf = mk2(aA[1][0], aA[1][2]) + mk2(aB[1][0], aB[1][2]);
            f32x2 pg = mk2(aA[2][0], aA[2][2]) + mk2(aB[2][0], aB[2][2]);
            f32x2 po = mk2(aA[3][0], aA[3][2]) + mk2(aB[3][0], aB[3][2]);
            f32x2 hh;
            FCELL(pi, pf, pg, po, hh);
            h1f32[hbase * HID + u]       = hh[0];
            h1f32[(hbase + 1) * HID + u] = hh[1];
        }
        __syncthreads();

        if (tid < MB * 32) {
            const int o  = tid & 31;
            const int rr = tid >> 5;
            float acc = fcb_lds[o];
            #pragma unroll 8
            for (int kk = 0; kk < HID; ++kk)
                acc += h1f32[rr * HID + kk] * fcw_lds[kk * 32 + o];
            out[(bbase + rr) * 32 + o] = fmaxf(acc, 0.f);
        }
    }
}

// ======================= fallback: R15 monolithic (273us) =======================
__global__ __launch_bounds__(512, 1) void lstm_feat_fallback(
    const float* __restrict__ x,
    const float* __restrict__ Wih0, const float* __restrict__ Whh0,
    const float* __restrict__ bih0, const float* __restrict__ bhh0,
    const float* __restrict__ Wih1, const float* __restrict__ Whh1,
    const float* __restrict__ bih1, const float* __restrict__ bhh1,
    const float* __restrict__ fcW, const float* __restrict__ fcb,
    float* __restrict__ out)
{
    __shared__ float x_lds[(MB / 2) * TSTEPS * 2];
    __shared__ __align__(16) _Float16 h0_lds[2][MB * RS];
    __shared__ __align__(16) _Float16 h1_lds[2][MB * RS];
    __shared__ float h1f32[MB * HID];
    __shared__ float fcw_lds[HID * 32];
    __shared__ float fcb_lds[32];

    const int tid  = threadIdx.x;
    const int wave = tid >> 6;
    const int lane = tid & 63;
    const int nq   = lane & 15;
    const int quad = lane >> 4;
    const int bbase = blockIdx.x * MB;
    const bool isL1 = (wave >= 4);
    const int ug = wave & 3;
    const int u  = ug * 16 + nq;

    for (int i = tid; i < TSTEPS * MB; i += 512) {
        int r = i >> 9, t = i & (TSTEPS - 1);
        x_lds[(r >> 1) * (TSTEPS * 2) + t * 2 + (r & 1)] = x[(bbase + r) * TSTEPS + t];
    }
    for (int i = tid; i < 32 * HID; i += 512) {
        int o = i >> 6, kk = i & 63;
        fcw_lds[kk * 32 + o] = fcW[i];
    }
    if (tid < 32) fcb_lds[tid] = fcb[tid];
    for (int i = tid; i < 2 * MB * RS; i += 512) {
        ((_Float16*)h0_lds)[i] = (_Float16)0.f;
        ((_Float16*)h1_lds)[i] = (_Float16)0.f;
    }

    f16x8 wA[4][2], wB[4][2];
    f32x4 cbias[4];
    float wx0s[4];
    {
        const float* Wa = isL1 ? Wih1 : Whh0;
        const float* Wb = isL1 ? Whh1 : Whh0;
        const float* bi = isL1 ? bih1 : bih0;
        const float* bh = isL1 ? bhh1 : bhh0;
        #pragma unroll
        for (int g = 0; g < 4; ++g) {
            const float sc = (g == 2) ? KTANH : KSIG;
            const int n = g * 64 + u;
            const float bs = (bi[n] + bh[n]) * sc;
            cbias[g] = (f32x4){bs, bs, bs, bs};
            wx0s[g] = Wih0[n] * sc;
            #pragma unroll
            for (int ks = 0; ks < 2; ++ks) {
                const int k0 = quad * 8 + ks * 32;
                f16x8 a, bb;
                #pragma unroll
                for (int j = 0; j < 8; ++j) {
                    a[j]  = (_Float16)(Wa[n * HID + k0 + j] * sc);
                    bb[j] = (_Float16)(Wb[n * HID + k0 + j] * sc);
                }
                wA[g][ks] = a; wB[g][ks] = bb;
            }
        }
    }

    const f32x4 zero4 = {0.f, 0.f, 0.f, 0.f};
    const int arow = (nq >> 1) * RS + quad * 8;
    const int b0r  = (quad * 2) * RS;
    const int hbase = quad * 2;
    f32x2 cc = mk2(0.f, 0.f);

    __syncthreads();

#define L0_SUBF(P, Q, XQ2) do {                                                      \
    f16x8 a0_ = *(const f16x8*)&h0_lds[P][arow];                                     \
    f16x8 a1_ = *(const f16x8*)&h0_lds[P][arow + 32];                                \
    f32x4 ac[4];                                                                     \
    __builtin_amdgcn_s_setprio(1);                                                   \
    _Pragma("unroll")                                                                \
    for (int g = 0; g < 4; ++g) ac[g] = MFMA16(a0_, wA[g][0], cbias[g]);             \
    _Pragma("unroll")                                                                \
    for (int g = 0; g < 4; ++g) ac[g] = MFMA16(a1_, wA[g][1], ac[g]);                \
    __builtin_amdgcn_s_setprio(0);                                                   \
    f32x2 pi = (XQ2) * wx0s[0] + mk2(ac[0][0], ac[0][2]);                            \
    f32x2 pf = (XQ2) * wx0s[1] + mk2(ac[1][0], ac[1][2]);                            \
    f32x2 pg = (XQ2) * wx0s[2] + mk2(ac[2][0], ac[2][2]);                            \
    f32x2 po = (XQ2) * wx0s[3] + mk2(ac[3][0], ac[3][2]);                            \
    f32x2 hh;                                                                        \
    FCELL(pi, pf, pg, po, hh);                                                       \
    h0_lds[Q][b0r + u]      = (_Float16)hh[0];                                       \
    h0_lds[Q][b0r + RS + u] = (_Float16)hh[1];                                       \
} while (0)

#define L1_SUBF(P, Q, GUARD) do {                                                    \
    f16x8 a00 = *(const f16x8*)&h0_lds[P][arow];                                     \
    f16x8 a01 = *(const f16x8*)&h0_lds[P][arow + 32];                                \
    f16x8 a10 = *(const f16x8*)&h1_lds[P][arow];                                     \
    f16x8 a11 = *(const f16x8*)&h1_lds[P][arow + 32];                                \
    f32x4 aA[4], aB[4];                                                              \
    __builtin_amdgcn_s_setprio(1);                                                   \
    _Pragma("unroll")                                                                \
    for (int g = 0; g < 4; ++g) aA[g] = MFMA16(a00, wA[g][0], zero4);                \
    _Pragma("unroll")                                                                \
    for (int g = 0; g < 4; ++g) aB[g] = MFMA16(a10, wB[g][0], cbias[g]);             \
    _Pragma("unroll")                                                                \
    for (int g = 0; g < 4; ++g) aA[g] = MFMA16(a01, wA[g][1], aA[g]);                \
    _Pragma("unroll")                                                                \
    for (int g = 0; g < 4; ++g) aB[g] = MFMA16(a11, wB[g][1], aB[g]);                \
    __builtin_amdgcn_s_setprio(0);                                                   \
    if (GUARD) {                                                                     \
        f32x2 pi = mk2(aA[0][0], aA[0][2]) + mk2(aB[0][0], aB[0][2]);                \
        f32x2 pf = mk2(aA[1][0], aA[1][2]) + mk2(aB[1][0], aB[1][2]);                \
        f32x2 pg = mk2(aA[2][0], aA[2][2]) + mk2(aB[2][0], aB[2][2]);                \
        f32x2 po = mk2(aA[3][0], aA[3][2]) + mk2(aB[3][0], aB[3][2]);                \
        f32x2 hh;                                                                    \
        FCELL(pi, pf, pg, po, hh);                                                   \
        h1_lds[Q][b0r + u]      = (_Float16)hh[0];                                   \
        h1_lds[Q][b0r + RS + u] = (_Float16)hh[1];                                   \
    }                                                                                \
} while (0)

    const int xoff = quad * (TSTEPS * 2);
    for (int k = 0; k < TSTEPS; k += 2) {
        f32x2 xa, xb;
        if (!isL1) {
            const f32x4 xv = *(const f32x4*)&x_lds[xoff + k * 2];
            xa = mk2(xv[0], xv[1]); xb = mk2(xv[2], xv[3]);
            L0_SUBF(0, 1, xa);
        } else {
            L1_SUBF(0, 1, (k > 0));
        }
        __syncthreads();
        if (!isL1) { L0_SUBF(1, 0, xb); } else { L1_SUBF(1, 0, true); }
        __syncthreads();
    }

    if (isL1) {
        f16x8 a00 = *(const f16x8*)&h0_lds[0][arow];
        f16x8 a01 = *(const f16x8*)&h0_lds[0][arow + 32];
        f16x8 a10 = *(const f16x8*)&h1_lds[0][arow];
        f16x8 a11 = *(const f16x8*)&h1_lds[0][arow + 32];
        f32x4 aA[4], aB[4];
        #pragma unroll
        for (int g = 0; g < 4; ++g) aA[g] = MFMA16(a00, wA[g][0], zero4);
        #pragma unroll
        for (int g = 0; g < 4; ++g) aB[g] = MFMA16(a10, wB[g][0], cbias[g]);
        #pragma unroll
        for (int g = 0; g < 4; ++g) aA[g] = MFMA16(a01, wA[g][1], aA[g]);
        #pragma unroll
        for (int g = 0; g < 4; ++g) aB[g] = MFMA16(a11, wB[g][1], aB[g]);
        f32x2 pi = mk2(aA[0][0], aA[0][2]) + mk2(aB[0][0], aB[0][2]);
        f32x2 pf = mk2(aA[1][0], aA[1][2]) + mk2(aB[1][0], aB[1][2]);
        f32x2 pg = mk2(aA[2][0], aA[2][2]) + mk2(aB[2][0], aB[2][2]);
        f32x2 po = mk2(aA[3][0], aA[3][2]) + mk2(aB[3][0], aB[3][2]);
        f32x2 hh;
        FCELL(pi, pf, pg, po, hh);
        h1f32[hbase * HID + u]       = hh[0];
        h1f32[(hbase + 1) * HID + u] = hh[1];
    }
    __syncthreads();

    if (tid < MB * 32) {
        const int o  = tid & 31;
        const int rr = tid >> 5;
        float acc = fcb_lds[o];
        #pragma unroll 8
        for (int kk = 0; kk < HID; ++kk)
            acc += h1f32[rr * HID + kk] * fcw_lds[kk * 32 + o];
        out[(bbase + rr) * 32 + o] = fmaxf(acc, 0.f);
    }
}

extern "C" void kernel_launch(void* const* d_in, const int* in_sizes, int n_in,
                              void* d_out, int out_size, void* d_ws, size_t ws_size,
                              hipStream_t stream) {
    const float* x    = (const float*)d_in[0];
    const float* Wih0 = (const float*)d_in[1];
    const float* Whh0 = (const float*)d_in[2];
    const float* bih0 = (const float*)d_in[3];
    const float* bhh0 = (const float*)d_in[4];
    const float* Wih1 = (const float*)d_in[5];
    const float* Whh1 = (const float*)d_in[6];
    const float* bih1 = (const float*)d_in[7];
    const float* bhh1 = (const float*)d_in[8];
    const float* fcW  = (const float*)d_in[9];
    const float* fcb  = (const float*)d_in[10];
    float* out = (float*)d_out;

    if (d_ws != nullptr && ws_size >= (size_t)WS_NEED) {
        (void)hipMemsetAsync(d_ws, 0, 2048, stream);   // zero flags each launch
        lstm_pc_kernel<<<512, 256, 0, stream>>>(
            x, Wih0, Whh0, bih0, bhh0, Wih1, Whh1, bih1, bhh1, fcW, fcb, out,
            (unsigned*)d_ws);
    } else {
        lstm_feat_fallback<<<256, 512, 0, stream>>>(
            x, Wih0, Whh0, bih0, bhh0, Wih1, Whh1, bih1, bhh1, fcW, fcb, out);
    }
}

// Round 15
// 323.155 us; speedup vs baseline: 10.9031x; 10.9031x over previous
//
#include <hip/hip_runtime.h>
#include <hip/hip_bf16.h>

// LSTMFeatureExtractor: 2-layer LSTM (H=64, IN=1, B=2048, T=512) + FC(64->32)+ReLU
// R18 = R13's 16-wave layout + R15's fused cell, cleanly (1 cell/lane, no
// duplicated trans). R17 (layer-split blocks over global) was catastrophic
// (ring traffic -> HBM, 3523us). R15 (273us) budget: MFMA 466 + VALU 563 +
// ~250 idle with only 2 carriers/SIMD. R13 proved 4 carriers/SIMD reachable
// but its cell duplicated trans (VALU 1010). Here: 16 waves (8 L0 + 8 L1,
// 8 units each, gate-pair tiles t0=i|f t1=g|o), L0 = 4 MFMA, L1 = 8 (accA/
// accB 2-chains), cell = 2 shfl_xor(8) swap + ONE scalar fused cell (7
// trans) per lane. Trans/SIMD/step = 28 (same as R15), MFMA same, 2x the
// latency carriers. Same LDS rings, 1 barrier/step, same numerics.

#define HID 64
#define TSTEPS 512
#define MB 8
#define RS 80   // f16 row stride: 160B

typedef _Float16 f16x8 __attribute__((ext_vector_type(8)));
typedef float f32x4 __attribute__((ext_vector_type(4)));

#define KSIG (-1.44269504089f)   // -log2(e)
#define KTANH (2.88539008178f)   // 2*log2(e)

#define MFMA16(A, B, C) __builtin_amdgcn_mfma_f32_16x16x32_f16((A), (B), (C), 0, 0, 0)

__global__ __launch_bounds__(1024, 1) void lstm_feat_kernel(
    const float* __restrict__ x,
    const float* __restrict__ Wih0, const float* __restrict__ Whh0,
    const float* __restrict__ bih0, const float* __restrict__ bhh0,
    const float* __restrict__ Wih1, const float* __restrict__ Whh1,
    const float* __restrict__ bih1, const float* __restrict__ bhh1,
    const float* __restrict__ fcW, const float* __restrict__ fcb,
    float* __restrict__ out)
{
    __shared__ __align__(16) float x_lds[4 * TSTEPS * 2];    // [qp][t][2], 16 KB
    __shared__ __align__(16) _Float16 h0_lds[2][MB * RS];    // ping-pong
    __shared__ __align__(16) _Float16 h1_lds[2][MB * RS];
    __shared__ float h1f32[MB * HID];
    __shared__ float fcw_lds[HID * 32];                      // transposed [k][o]
    __shared__ float fcb_lds[32];

    const int tid  = threadIdx.x;
    const int wave = tid >> 6;          // 0..15
    const int lane = tid & 63;
    const int nq   = lane & 15;
    const int quad = lane >> 4;
    const int bbase = blockIdx.x * MB;
    const bool isL1 = (wave >= 8);      // waves 0-7: layer0, 8-15: layer1
    const int oct  = (wave & 7) * 8;    // this wave's 8 units
    const bool lo  = (nq < 8);

    // ---- one-time staging ----
    for (int i = tid; i < TSTEPS * MB; i += 1024) {
        int r = i >> 9, t = i & (TSTEPS - 1);
        x_lds[(r >> 1) * (TSTEPS * 2) + t * 2 + (r & 1)] = x[(bbase + r) * TSTEPS + t];
    }
    for (int i = tid; i < 32 * HID; i += 1024) {
        int o = i >> 6, kk = i & 63;
        fcw_lds[kk * 32 + o] = fcW[i];
    }
    if (tid < 32) fcb_lds[tid] = fcb[tid];
    for (int i = tid; i < 2 * MB * RS; i += 1024) {
        ((_Float16*)h0_lds)[i] = (_Float16)0.f;
        ((_Float16*)h1_lds)[i] = (_Float16)0.f;
    }

    // ---- per-lane columns: tile t in {0,1}: gate = 2t+(nq>>3), unit = oct+(nq&7)
    //      (PyTorch gate order i,f,g,o: t0 = i|f, t1 = g|o). All PRE-SCALED. ----
    f16x8 w0[2][2], wi1[2][2], wh1[2][2];
    float bs0[2], wx0[2];
    f32x4 cb1[2];
    #pragma unroll
    for (int t = 0; t < 2; ++t) {
        const int gate = 2 * t + (nq >> 3);
        const int n = gate * 64 + oct + (nq & 7);
        const float sc = (gate == 2) ? KTANH : KSIG;
        if (!isL1) {
            bs0[t] = (bih0[n] + bhh0[n]) * sc;
            wx0[t] = Wih0[n] * sc;                  // IN==1
            #pragma unroll
            for (int ks = 0; ks < 2; ++ks) {
                const int k0 = quad * 8 + ks * 32;
                f16x8 a;
                #pragma unroll
                for (int j = 0; j < 8; ++j)
                    a[j] = (_Float16)(Whh0[n * HID + k0 + j] * sc);
                w0[t][ks] = a;
            }
        } else {
            const float cb = (bih1[n] + bhh1[n]) * sc;
            cb1[t] = (f32x4){cb, cb, cb, cb};
            #pragma unroll
            for (int ks = 0; ks < 2; ++ks) {
                const int k0 = quad * 8 + ks * 32;
                f16x8 a, b;
                #pragma unroll
                for (int j = 0; j < 8; ++j) {
                    a[j] = (_Float16)(Wih1[n * HID + k0 + j] * sc);
                    b[j] = (_Float16)(Whh1[n * HID + k0 + j] * sc);
                }
                wi1[t][ks] = a; wh1[t][ks] = b;
            }
        }
    }

    // A row m carries h[m>>1]; lane reads A-row nq -> batch nq>>1.
    // D elem e (row quad*4+e) -> batch 2q+(e>>1): elems 0,2 used.
    const int arow = (nq >> 1) * RS + quad * 8;
    // cell identity: lane -> (b = 2q + (nq>>3), u = oct + (nq&7))
    const int wrow = (quad * 2 + (lo ? 0 : 1)) * RS + oct + (nq & 7);
    const int wfc  = (quad * 2 + (lo ? 0 : 1)) * HID + oct + (nq & 7);
    float cst = 0.f;                    // this lane's single cell state
    const f32x4 zero4 = {0.f, 0.f, 0.f, 0.f};

    __syncthreads();

// ---- exchange (2 shfl) + ONE fused scalar cell (7 trans) per lane ----
// lo lane owns (i,g) of b=2q [elem0]; hi lane owns (f,o) of b=2q+1 via its
// elem2... exchange complementary halves so each lane gets all 4 pre-acts
// of ITS batch. E0T/E2T = tile T pre-act elems 0/2 (post accA+accB for L1).
#define CELL1(E00, E20, E01, E21, HOUT) do {                                      \
    float s0 = __shfl_xor(lo ? (E20) : (E00), 8);                                 \
    float s1 = __shfl_xor(lo ? (E21) : (E01), 8);                                 \
    float pi = lo ? (E00) : s0;                                                   \
    float pf = lo ? s0 : (E20);                                                   \
    float pg = lo ? (E01) : s1;                                                   \
    float po = lo ? s1 : (E21);                                                   \
    float ea = __builtin_amdgcn_exp2f(pi), eb = __builtin_amdgcn_exp2f(pf);       \
    float eg = __builtin_amdgcn_exp2f(pg), ed = __builtin_amdgcn_exp2f(po);       \
    float Aq = ea + 1.f, Bq = eb + 1.f, Gp = eg + 1.f, Dn = ed + 1.f;             \
    float AG = Aq * Gp;                                                           \
    float r1 = __builtin_amdgcn_rcpf(AG * Bq);                                    \
    cst = (cst * AG + (eg - 1.f) * Bq) * r1;                                      \
    float E = __builtin_amdgcn_exp2f(cst * KTANH);                                \
    float r2 = __builtin_amdgcn_rcpf(Dn * (E + 1.f));                             \
    HOUT = (E - 1.f) * r2;                                                        \
} while (0)

// ---- L0 substep: H0 buf P + x -> H0 buf Q (4 MFMA: 2 indep 2-chains) ----
#define L0_SUB(P, Q, XA, XB) do {                                                 \
    f16x8 a0 = *(const f16x8*)&h0_lds[P][arow];                                   \
    f16x8 a1 = *(const f16x8*)&h0_lds[P][arow + 32];                              \
    f32x4 A[2];                                                                   \
    __builtin_amdgcn_s_setprio(1);                                                \
    _Pragma("unroll")                                                             \
    for (int t = 0; t < 2; ++t) {                                                 \
        const float v0 = fmaf((XA), wx0[t], bs0[t]);                              \
        const float v1 = fmaf((XB), wx0[t], bs0[t]);                              \
        f32x4 C = {v0, 0.f, v1, 0.f};                                             \
        A[t] = MFMA16(a0, w0[t][0], C);                                           \
    }                                                                             \
    _Pragma("unroll")                                                             \
    for (int t = 0; t < 2; ++t) A[t] = MFMA16(a1, w0[t][1], A[t]);                \
    __builtin_amdgcn_s_setprio(0);                                                \
    float hv;                                                                     \
    CELL1(A[0][0], A[0][2], A[1][0], A[1][2], hv);                                \
    h0_lds[Q][wrow] = (_Float16)hv;                                               \
} while (0)

// ---- L1 substep: H0 buf P + H1 buf P -> H1 buf Q (8 MFMA: 4 indep 2-chains) ----
#define L1_SUB(P, Q, GUARD) do {                                                  \
    f16x8 a00 = *(const f16x8*)&h0_lds[P][arow];                                  \
    f16x8 a01 = *(const f16x8*)&h0_lds[P][arow + 32];                             \
    f16x8 a10 = *(const f16x8*)&h1_lds[P][arow];                                  \
    f16x8 a11 = *(const f16x8*)&h1_lds[P][arow + 32];                             \
    f32x4 aA[2], aB[2];                                                           \
    __builtin_amdgcn_s_setprio(1);                                                \
    _Pragma("unroll")                                                             \
    for (int t = 0; t < 2; ++t) aA[t] = MFMA16(a00, wi1[t][0], zero4);            \
    _Pragma("unroll")                                                             \
    for (int t = 0; t < 2; ++t) aB[t] = MFMA16(a10, wh1[t][0], cb1[t]);           \
    _Pragma("unroll")                                                             \
    for (int t = 0; t < 2; ++t) aA[t] = MFMA16(a01, wi1[t][1], aA[t]);            \
    _Pragma("unroll")                                                             \
    for (int t = 0; t < 2; ++t) aB[t] = MFMA16(a11, wh1[t][1], aB[t]);            \
    __builtin_amdgcn_s_setprio(0);                                                \
    if (GUARD) {                                                                  \
        float e00 = aA[0][0] + aB[0][0], e20 = aA[0][2] + aB[0][2];               \
        float e01 = aA[1][0] + aB[1][0], e21 = aA[1][2] + aB[1][2];               \
        float hv;                                                                 \
        CELL1(e00, e20, e01, e21, hv);                                            \
        h1_lds[Q][wrow] = (_Float16)hv;                                           \
    }                                                                             \
} while (0)

    // ---- skewed recurrence, unrolled x2 (buffers 0->1 then 1->0) ----
    const int xoff = quad * (TSTEPS * 2);
    for (int k = 0; k < TSTEPS; k += 2) {
        float xa0, xa1, xb0, xb1;
        if (!isL1) {
            const f32x4 xv = *(const f32x4*)&x_lds[xoff + k * 2];
            xa0 = xv[0]; xa1 = xv[1]; xb0 = xv[2]; xb1 = xv[3];
        }
        if (!isL1) { L0_SUB(0, 1, xa0, xa1); } else { L1_SUB(0, 1, (k > 0)); }
        __syncthreads();
        if (!isL1) { L0_SUB(1, 0, xb0, xb1); } else { L1_SUB(1, 0, true); }
        __syncthreads();
    }

    // ---- peeled final L1 step: H1[512] from H0[512] (buf 0), H1[511] (buf 0) ----
    if (isL1) {
        f16x8 a00 = *(const f16x8*)&h0_lds[0][arow];
        f16x8 a01 = *(const f16x8*)&h0_lds[0][arow + 32];
        f16x8 a10 = *(const f16x8*)&h1_lds[0][arow];
        f16x8 a11 = *(const f16x8*)&h1_lds[0][arow + 32];
        f32x4 aA[2], aB[2];
        #pragma unroll
        for (int t = 0; t < 2; ++t) aA[t] = MFMA16(a00, wi1[t][0], zero4);
        #pragma unroll
        for (int t = 0; t < 2; ++t) aB[t] = MFMA16(a10, wh1[t][0], cb1[t]);
        #pragma unroll
        for (int t = 0; t < 2; ++t) aA[t] = MFMA16(a01, wi1[t][1], aA[t]);
        #pragma unroll
        for (int t = 0; t < 2; ++t) aB[t] = MFMA16(a11, wh1[t][1], aB[t]);
        float e00 = aA[0][0] + aB[0][0], e20 = aA[0][2] + aB[0][2];
        float e01 = aA[1][0] + aB[1][0], e21 = aA[1][2] + aB[1][2];
        float hv;
        CELL1(e00, e20, e01, e21, hv);
        h1f32[wfc] = hv;
    }
    __syncthreads();

    // ---- epilogue: features = relu(H1[512] @ fcW^T + fcb) ----
    if (tid < MB * 32) {
        const int o  = tid & 31;
        const int rr = tid >> 5;
        float acc = fcb_lds[o];
        #pragma unroll 8
        for (int kk = 0; kk < HID; ++kk)
            acc += h1f32[rr * HID + kk] * fcw_lds[kk * 32 + o];
        out[(bbase + rr) * 32 + o] = fmaxf(acc, 0.f);
    }
}

extern "C" void kernel_launch(void* const* d_in, const int* in_sizes, int n_in,
                              void* d_out, int out_size, void* d_ws, size_t ws_size,
                              hipStream_t stream) {
    const float* x    = (const float*)d_in[0];
    const float* Wih0 = (const float*)d_in[1];
    const float* Whh0 = (const float*)d_in[2];
    const float* bih0 = (const float*)d_in[3];
    const float* bhh0 = (const float*)d_in[4];
    const float* Wih1 = (const float*)d_in[5];
    const float* Whh1 = (const float*)d_in[6];
    const float* bih1 = (const float*)d_in[7];
    const float* bhh1 = (const float*)d_in[8];
    const float* fcW  = (const float*)d_in[9];
    const float* fcb  = (const float*)d_in[10];
    float* out = (float*)d_out;

    lstm_feat_kernel<<<2048 / MB, 1024, 0, stream>>>(
        x, Wih0, Whh0, bih0, bhh0, Wih1, Whh1, bih1, bhh1, fcW, fcb, out);
}

// Round 16
// 301.935 us; speedup vs baseline: 11.6694x; 1.0703x over previous
//
#include <hip/hip_runtime.h>
#include <hip/hip_bf16.h>

// LSTMFeatureExtractor: 2-layer LSTM (H=64, IN=1, B=2048, T=512) + FC(64->32)+ReLU
// R19 = FINAL: restore R15 (best, 273us). Structural search complete:
// R9 (reg prefetch) neutral; R11 (flags) -45%; R12 (forced anti-phase) -8%;
// R13/R18 (16 waves, dirty/clean cell) -23%/-11%; R14 (dual chains) -22%;
// R16 (batch-split blocks) -40%; R17 (layer-split global ring) -12x.
// Wins: R8 VALU diet + R15 algebraic trans fusion (340 -> 273us).
// Floor arithmetic (per SIMD per step): MFMA issue 466cy (irreducible at
// 8 batches/CU; M=8<16 half-tile waste; MB=16 halves active CUs and doubles
// per-SIMD cell VALU), fused-cell VALU ~560cy (28 trans-instr/SIMD/step,
// algebraically minimal), barrier+chain latency ~250cy (unhideable with 2
// lockstep waves; all alternatives regressed). Step ~1280cy x 512 = 273us.
// Kernel: wave-specialized L0/L1 (4+4 waves), prescaled weights (KSIG/KTANH
// folded), bias/x in MFMA C operand, fused 7-trans cell:
//   c' = [c*A*Gp + (G-1)*B] * rcp(A*B*Gp);  h = (E-1)*rcp(Dn*(E+1))
// with A=1+2^pi, B=1+2^pf, G=2^pg, Gp=1+G, Dn=1+2^po, E=2^(KT*c').
// Packed f32x2 cells, k-unroll x2 ping-pong LDS, setprio on MFMA clusters.

#define HID 64
#define TSTEPS 512
#define MB 8
#define RS 80   // f16 row stride: 160B

typedef _Float16 f16x8 __attribute__((ext_vector_type(8)));
typedef float f32x4 __attribute__((ext_vector_type(4)));
typedef float f32x2 __attribute__((ext_vector_type(2)));

#define KSIG (-1.44269504089f)   // -log2(e)
#define KTANH (2.88539008178f)   // 2*log2(e)

__device__ __forceinline__ f32x2 mk2(float a, float b) { f32x2 r; r[0] = a; r[1] = b; return r; }
__device__ __forceinline__ f32x2 exp2v(f32x2 v) {
    f32x2 r; r[0] = __builtin_amdgcn_exp2f(v[0]); r[1] = __builtin_amdgcn_exp2f(v[1]); return r;
}
__device__ __forceinline__ f32x2 rcpv(f32x2 v) {
    f32x2 r; r[0] = __builtin_amdgcn_rcpf(v[0]); r[1] = __builtin_amdgcn_rcpf(v[1]); return r;
}

__global__ __launch_bounds__(512, 1) void lstm_feat_kernel(
    const float* __restrict__ x,
    const float* __restrict__ Wih0, const float* __restrict__ Whh0,
    const float* __restrict__ bih0, const float* __restrict__ bhh0,
    const float* __restrict__ Wih1, const float* __restrict__ Whh1,
    const float* __restrict__ bih1, const float* __restrict__ bhh1,
    const float* __restrict__ fcW, const float* __restrict__ fcb,
    float* __restrict__ out)
{
    __shared__ float x_lds[(MB / 2) * TSTEPS * 2];          // [qp][t][2], 16 KB
    __shared__ __align__(16) _Float16 h0_lds[2][MB * RS];
    __shared__ __align__(16) _Float16 h1_lds[2][MB * RS];
    __shared__ float h1f32[MB * HID];
    __shared__ float fcw_lds[HID * 32];                     // transposed [k][o]
    __shared__ float fcb_lds[32];

    const int tid  = threadIdx.x;
    const int wave = tid >> 6;
    const int lane = tid & 63;
    const int nq   = lane & 15;
    const int quad = lane >> 4;
    const int bbase = blockIdx.x * MB;
    const bool isL1 = (wave >= 4);     // waves 0-3: layer0, waves 4-7: layer1
    const int ug = wave & 3;
    const int u  = ug * 16 + nq;       // hidden unit owned by this lane

    // ---- one-time staging ----
    for (int i = tid; i < TSTEPS * MB; i += 512) {
        int r = i >> 9, t = i & (TSTEPS - 1);
        x_lds[(r >> 1) * (TSTEPS * 2) + t * 2 + (r & 1)] = x[(bbase + r) * TSTEPS + t];
    }
    for (int i = tid; i < 32 * HID; i += 512) {
        int o = i >> 6, kk = i & 63;
        fcw_lds[kk * 32 + o] = fcW[i];
    }
    if (tid < 32) fcb_lds[tid] = fcb[tid];
    for (int i = tid; i < 2 * MB * RS; i += 512) {
        ((_Float16*)h0_lds)[i] = (_Float16)0.f;
        ((_Float16*)h1_lds)[i] = (_Float16)0.f;
    }

    // ---- per-lane weight fragments, PRE-SCALED by gate constant ----
    // L0 waves: wA = Whh0. L1 waves: wA = Wih1, wB = Whh1.
    f16x8 wA[4][2], wB[4][2];
    f32x4 cbias[4];                    // scaled bias splat -> MFMA C operand
    float wx0s[4];
    {
        const float* Wa = isL1 ? Wih1 : Whh0;
        const float* Wb = isL1 ? Whh1 : Whh0;
        const float* bi = isL1 ? bih1 : bih0;
        const float* bh = isL1 ? bhh1 : bhh0;
        #pragma unroll
        for (int g = 0; g < 4; ++g) {
            const float sc = (g == 2) ? KTANH : KSIG;
            const int n = g * 64 + u;
            const float bs = (bi[n] + bh[n]) * sc;
            cbias[g] = (f32x4){bs, bs, bs, bs};
            wx0s[g] = Wih0[n] * sc;    // IN==1 (L0 waves only)
            #pragma unroll
            for (int ks = 0; ks < 2; ++ks) {
                const int k0 = quad * 8 + ks * 32;
                f16x8 a, b;
                #pragma unroll
                for (int j = 0; j < 8; ++j) {
                    a[j] = (_Float16)(Wa[n * HID + k0 + j] * sc);
                    b[j] = (_Float16)(Wb[n * HID + k0 + j] * sc);
                }
                wA[g][ks] = a; wB[g][ks] = b;
            }
        }
    }

    const f32x4 zero4 = {0.f, 0.f, 0.f, 0.f};
    // A row m carries h[m>>1]; D row quad*4+reg -> batch (quad*4+reg)>>1:
    // regs {0,1}->b0 (use elem 0), {2,3}->b0+1 (use elem 2).
    const int arow = (nq >> 1) * RS + quad * 8;
    const int b0r  = (quad * 2) * RS;  // byte-row of this lane's first batch
    const int hbase = quad * 2;        // first batch row index
    f32x2 cc = mk2(0.f, 0.f);          // packed cell state (both batch rows)

    __syncthreads();

// ---- fused cell: pre-acts PI,PF,PG,PO (packed, prescaled) -> updates cc,
//      produces hh. 7 trans/cell: 5 exp2 + 2 rcp. ----
#define FCELL(PI, PF, PG, PO, HH) do {                                               \
    f32x2 ea = exp2v(PI), eb = exp2v(PF), eg = exp2v(PG), ed = exp2v(PO);            \
    f32x2 Aq = ea + 1.f, Bq = eb + 1.f, Gp = eg + 1.f, Dn = ed + 1.f;                \
    f32x2 AG = Aq * Gp;                                                              \
    f32x2 r1 = rcpv(AG * Bq);                                                        \
    f32x2 nm = cc * AG + (eg - 1.f) * Bq;                                            \
    cc = nm * r1;                                                                    \
    f32x2 E  = exp2v(cc * KTANH);                                                    \
    f32x2 r2 = rcpv(Dn * (E + 1.f));                                                 \
    HH = (E - 1.f) * r2;                                                             \
} while (0)

// ---- one layer-0 substep, compile-time buffers P->Q ----
#define L0_SUB(P, Q, XQ2) do {                                                       \
    f16x8 a0_ = *(const f16x8*)&h0_lds[P][arow];                                     \
    f16x8 a1_ = *(const f16x8*)&h0_lds[P][arow + 32];                                \
    f32x4 ac[4];                                                                     \
    __builtin_amdgcn_s_setprio(1);                                                   \
    _Pragma("unroll")                                                                \
    for (int g = 0; g < 4; ++g)                                                      \
        ac[g] = __builtin_amdgcn_mfma_f32_16x16x32_f16(a0_, wA[g][0], cbias[g], 0, 0, 0); \
    _Pragma("unroll")                                                                \
    for (int g = 0; g < 4; ++g)                                                      \
        ac[g] = __builtin_amdgcn_mfma_f32_16x16x32_f16(a1_, wA[g][1], ac[g], 0, 0, 0); \
    __builtin_amdgcn_s_setprio(0);                                                   \
    f32x2 pi = (XQ2) * wx0s[0] + mk2(ac[0][0], ac[0][2]);                            \
    f32x2 pf = (XQ2) * wx0s[1] + mk2(ac[1][0], ac[1][2]);                            \
    f32x2 pg = (XQ2) * wx0s[2] + mk2(ac[2][0], ac[2][2]);                            \
    f32x2 po = (XQ2) * wx0s[3] + mk2(ac[3][0], ac[3][2]);                            \
    f32x2 hh;                                                                        \
    FCELL(pi, pf, pg, po, hh);                                                       \
    h0_lds[Q][b0r + u]      = (_Float16)hh[0];                                       \
    h0_lds[Q][b0r + RS + u] = (_Float16)hh[1];                                       \
} while (0)

// ---- one layer-1 substep; GUARD=false suppresses the k==0 commit ----
#define L1_SUB(P, Q, GUARD) do {                                                     \
    f16x8 a00 = *(const f16x8*)&h0_lds[P][arow];                                     \
    f16x8 a01 = *(const f16x8*)&h0_lds[P][arow + 32];                                \
    f16x8 a10 = *(const f16x8*)&h1_lds[P][arow];                                     \
    f16x8 a11 = *(const f16x8*)&h1_lds[P][arow + 32];                                \
    f32x4 aA[4], aB[4];                                                              \
    __builtin_amdgcn_s_setprio(1);                                                   \
    _Pragma("unroll")                                                                \
    for (int g = 0; g < 4; ++g)                                                      \
        aA[g] = __builtin_amdgcn_mfma_f32_16x16x32_f16(a00, wA[g][0], zero4, 0, 0, 0); \
    _Pragma("unroll")                                                                \
    for (int g = 0; g < 4; ++g)                                                      \
        aB[g] = __builtin_amdgcn_mfma_f32_16x16x32_f16(a10, wB[g][0], cbias[g], 0, 0, 0); \
    _Pragma("unroll")                                                                \
    for (int g = 0; g < 4; ++g)                                                      \
        aA[g] = __builtin_amdgcn_mfma_f32_16x16x32_f16(a01, wA[g][1], aA[g], 0, 0, 0); \
    _Pragma("unroll")                                                                \
    for (int g = 0; g < 4; ++g)                                                      \
        aB[g] = __builtin_amdgcn_mfma_f32_16x16x32_f16(a11, wB[g][1], aB[g], 0, 0, 0); \
    __builtin_amdgcn_s_setprio(0);                                                   \
    if (GUARD) {                                                                     \
        f32x2 pi = mk2(aA[0][0], aA[0][2]) + mk2(aB[0][0], aB[0][2]);                \
        f32x2 pf = mk2(aA[1][0], aA[1][2]) + mk2(aB[1][0], aB[1][2]);                \
        f32x2 pg = mk2(aA[2][0], aA[2][2]) + mk2(aB[2][0], aB[2][2]);                \
        f32x2 po = mk2(aA[3][0], aA[3][2]) + mk2(aB[3][0], aB[3][2]);                \
        f32x2 hh;                                                                    \
        FCELL(pi, pf, pg, po, hh);                                                   \
        h1_lds[Q][b0r + u]      = (_Float16)hh[0];                                   \
        h1_lds[Q][b0r + RS + u] = (_Float16)hh[1];                                   \
    }                                                                                \
} while (0)

    // ---- skewed recurrence, unrolled x2 (buffers 0->1 then 1->0) ----
    const int xoff = quad * (TSTEPS * 2);
    for (int k = 0; k < TSTEPS; k += 2) {
        f32x2 xa, xb;
        if (!isL1) {
            const f32x4 xv = *(const f32x4*)&x_lds[xoff + k * 2];
            xa = mk2(xv[0], xv[1]); xb = mk2(xv[2], xv[3]);
            L0_SUB(0, 1, xa);
        } else {
            L1_SUB(0, 1, (k > 0));
        }
        __syncthreads();
        if (!isL1) {
            L0_SUB(1, 0, xb);
        } else {
            L1_SUB(1, 0, true);
        }
        __syncthreads();
    }

    // ---- peeled final layer-1 step: H1[512] from H0[512] (buf 0), H1[511] ----
    if (isL1) {
        f16x8 a00 = *(const f16x8*)&h0_lds[0][arow];
        f16x8 a01 = *(const f16x8*)&h0_lds[0][arow + 32];
        f16x8 a10 = *(const f16x8*)&h1_lds[0][arow];
        f16x8 a11 = *(const f16x8*)&h1_lds[0][arow + 32];
        f32x4 aA[4], aB[4];
        #pragma unroll
        for (int g = 0; g < 4; ++g)
            aA[g] = __builtin_amdgcn_mfma_f32_16x16x32_f16(a00, wA[g][0], zero4, 0, 0, 0);
        #pragma unroll
        for (int g = 0; g < 4; ++g)
            aB[g] = __builtin_amdgcn_mfma_f32_16x16x32_f16(a10, wB[g][0], cbias[g], 0, 0, 0);
        #pragma unroll
        for (int g = 0; g < 4; ++g)
            aA[g] = __builtin_amdgcn_mfma_f32_16x16x32_f16(a01, wA[g][1], aA[g], 0, 0, 0);
        #pragma unroll
        for (int g = 0; g < 4; ++g)
            aB[g] = __builtin_amdgcn_mfma_f32_16x16x32_f16(a11, wB[g][1], aB[g], 0, 0, 0);
        f32x2 pi = mk2(aA[0][0], aA[0][2]) + mk2(aB[0][0], aB[0][2]);
        f32x2 pf = mk2(aA[1][0], aA[1][2]) + mk2(aB[1][0], aB[1][2]);
        f32x2 pg = mk2(aA[2][0], aA[2][2]) + mk2(aB[2][0], aB[2][2]);
        f32x2 po = mk2(aA[3][0], aA[3][2]) + mk2(aB[3][0], aB[3][2]);
        f32x2 hh;
        FCELL(pi, pf, pg, po, hh);
        h1f32[hbase * HID + u]       = hh[0];
        h1f32[(hbase + 1) * HID + u] = hh[1];
    }
    __syncthreads();

    // ---- epilogue: features = relu(H1[512] @ fcW^T + fcb) ----
    if (tid < MB * 32) {
        const int o  = tid & 31;
        const int rr = tid >> 5;
        float acc = fcb_lds[o];
        #pragma unroll 8
        for (int kk = 0; kk < HID; ++kk)
            acc += h1f32[rr * HID + kk] * fcw_lds[kk * 32 + o];
        out[(bbase + rr) * 32 + o] = fmaxf(acc, 0.f);
    }
}

extern "C" void kernel_launch(void* const* d_in, const int* in_sizes, int n_in,
                              void* d_out, int out_size, void* d_ws, size_t ws_size,
                              hipStream_t stream) {
    const float* x    = (const float*)d_in[0];
    const float* Wih0 = (const float*)d_in[1];
    const float* Whh0 = (const float*)d_in[2];
    const float* bih0 = (const float*)d_in[3];
    const float* bhh0 = (const float*)d_in[4];
    const float* Wih1 = (const float*)d_in[5];
    const float* Whh1 = (const float*)d_in[6];
    const float* bih1 = (const float*)d_in[7];
    const float* bhh1 = (const float*)d_in[8];
    const float* fcW  = (const float*)d_in[9];
    const float* fcb  = (const float*)d_in[10];
    float* out = (float*)d_out;

    lstm_feat_kernel<<<2048 / MB, 512, 0, stream>>>(
        x, Wih0, Whh0, bih0, bhh0, Wih1, Whh1, bih1, bhh1, fcW, fcb, out);
}